// Round 2
// baseline (332.165 us; speedup 1.0000x reference)
//
#include <hip/hip_runtime.h>

#define K_CLASSES 150
#define C_CH      768
#define HW4       1024            // 64*64/4 float4 per (b,c) plane
#define PLANES    (16 * C_CH)     // 12288 (b,c) planes

// ---------------------------------------------------------------------------
// Kernel A: per-class-row max and 1/sum(exp) for a numerically stable softmax.
// One block per row (K=150 blocks), 256 threads, 3 channels/thread.
// (unchanged — harness-verified)
// ---------------------------------------------------------------------------
__global__ __launch_bounds__(256) void row_stats(const float* __restrict__ ca,
                                                 float* __restrict__ rowmax,
                                                 float* __restrict__ rowinv) {
    const int k = blockIdx.x;
    const float* row = ca + (size_t)k * C_CH;
    const int t = threadIdx.x;

    float v0 = row[t];
    float v1 = row[t + 256];
    float v2 = row[t + 512];

    // block max
    float m = fmaxf(v0, fmaxf(v1, v2));
    #pragma unroll
    for (int off = 32; off > 0; off >>= 1)
        m = fmaxf(m, __shfl_down(m, off, 64));
    __shared__ float sm[4];
    __shared__ float ss[4];
    const int wave = t >> 6, lane = t & 63;
    if (lane == 0) sm[wave] = m;
    __syncthreads();
    if (t == 0) sm[0] = fmaxf(fmaxf(sm[0], sm[1]), fmaxf(sm[2], sm[3]));
    __syncthreads();
    m = sm[0];

    // block sum of exp
    float e = expf(v0 - m) + expf(v1 - m) + expf(v2 - m);
    #pragma unroll
    for (int off = 32; off > 0; off >>= 1)
        e += __shfl_down(e, off, 64);
    if (lane == 0) ss[wave] = e;
    __syncthreads();
    if (t == 0) {
        float s = ss[0] + ss[1] + ss[2] + ss[3];
        rowmax[k] = m;
        rowinv[k] = 1.0f / s;
    }
}

// ---------------------------------------------------------------------------
// Kernel B: scale[c] = sum_k exp(ca[k,c] - rowmax[k]) * rowinv[k]
// 768 threads total (3 blocks x 256). (unchanged — harness-verified)
// ---------------------------------------------------------------------------
__global__ __launch_bounds__(256) void col_scale(const float* __restrict__ ca,
                                                 const float* __restrict__ rowmax,
                                                 const float* __restrict__ rowinv,
                                                 float* __restrict__ scale) {
    const int c = blockIdx.x * 256 + threadIdx.x;   // 0..767
    float acc = 0.0f;
    #pragma unroll 10
    for (int k = 0; k < K_CLASSES; ++k) {
        acc += expf(ca[(size_t)k * C_CH + c] - rowmax[k]) * rowinv[k];
    }
    scale[c] = acc;
}

// ---------------------------------------------------------------------------
// Kernel C: out = x * scale[c]. Grid-stride over (b,c) planes, 2048 blocks
// (G11 streaming pattern), 256 threads, 4 float4/thread/plane, fully
// coalesced 16B/lane. Non-temporal load/store: x and out have zero reuse,
// 384 MB working set would otherwise thrash L3 (256 MB) every iteration.
// scale[c] is plane-uniform -> scalar broadcast.
// ---------------------------------------------------------------------------
typedef float vf4 __attribute__((ext_vector_type(4)));

__global__ __launch_bounds__(256) void apply_scale(const vf4* __restrict__ x,
                                                   const float* __restrict__ scale,
                                                   vf4* __restrict__ out) {
    const int t = threadIdx.x;
    for (int plane = blockIdx.x; plane < PLANES; plane += gridDim.x) {
        const int c = plane % C_CH;
        const float s = scale[c];
        const size_t base = (size_t)plane * HW4;
        #pragma unroll
        for (int j = 0; j < 4; ++j) {
            const size_t i = base + t + j * 256;
            vf4 v = __builtin_nontemporal_load(&x[i]);
            v *= s;
            __builtin_nontemporal_store(v, &out[i]);
        }
    }
}

extern "C" void kernel_launch(void* const* d_in, const int* in_sizes, int n_in,
                              void* d_out, int out_size, void* d_ws, size_t ws_size,
                              hipStream_t stream) {
    const float* x  = (const float*)d_in[0];   // (16, 768, 64, 64) fp32
    const float* ca = (const float*)d_in[1];   // (150, 768) fp32
    float* out = (float*)d_out;

    float* ws     = (float*)d_ws;
    float* rowmax = ws;           // 150 floats
    float* rowinv = ws + 256;     // 150 floats
    float* scale  = ws + 512;     // 768 floats

    row_stats<<<K_CLASSES, 256, 0, stream>>>(ca, rowmax, rowinv);
    col_scale<<<3, 256, 0, stream>>>(ca, rowmax, rowinv, scale);

    apply_scale<<<2048, 256, 0, stream>>>((const vf4*)x, scale, (vf4*)out);
}